// Round 9
// baseline (185.404 us; speedup 1.0000x reference)
//
#include <hip/hip_runtime.h>

// EuclideanCodebook: fp16 MFMA distance GEMM (m97-style 128x128 tile, BK=64,
// double-buffered global_load_lds, swizzled LDS) + top-2 margin flag
// + split-K exact fp32 rescue.
// x: [N=32768][256] f32, embedding_sum: [K=2048][256] f32, usage: [K] f32
// out: quantized [N*256] f32, codes [N] f32

#define EPSV 1e-5f
#define DDIM 256
#define TAU  0.4f
#define NCB  16      // cluster blocks (2048/128)
#define RPB  8       // rescue rows per group
#define KSPL 4       // rescue K split

typedef __attribute__((ext_vector_type(8))) _Float16 f16x8;
typedef __attribute__((ext_vector_type(4))) float f32x4;
typedef unsigned short u16;
typedef unsigned long long u64;

__device__ __forceinline__ u16 f2h(float f) {
    f = fminf(fmaxf(f, -60000.f), 60000.f);   // keep fp16 finite
    const _Float16 h = (_Float16)f;
    return __builtin_bit_cast(u16, h);
}
__device__ __forceinline__ u64 packdk(float d, int k) {
    unsigned u = __builtin_bit_cast(unsigned, d);
    u = (u & 0x80000000u) ? ~u : (u | 0x80000000u);   // sortable float
    return ((u64)u << 32) | (unsigned)k;
}

// ---------------- prep_e: emb, emb_t, e fp16, ||e||^2; zero counter ---------
__global__ void prep_e(const float* __restrict__ esum,
                       const float* __restrict__ usage,
                       float* __restrict__ emb,     // [K][256] f32
                       float* __restrict__ emb_t,   // [256][K] f32
                       u16* __restrict__ eh,        // [K][256] f16 bits
                       float* __restrict__ enorm2,  // [K]
                       int* __restrict__ counter,
                       int K) {
    if (blockIdx.x == 0 && threadIdx.x == 0) *counter = 0;
    const int k = blockIdx.x;
    const int d = threadIdx.x;                 // 256 threads
    const float u = fmaxf(usage[k], EPSV);
    const float e = esum[k * DDIM + d] / u;
    emb[k * DDIM + d] = e;
    emb_t[(size_t)d * K + k] = e;
    eh[k * DDIM + d] = f2h(e);

    float s = e * e;
    #pragma unroll
    for (int off = 32; off > 0; off >>= 1) s += __shfl_down(s, off, 64);
    __shared__ float ws[4];
    if ((threadIdx.x & 63) == 0) ws[threadIdx.x >> 6] = s;
    __syncthreads();
    if (threadIdx.x == 0) enorm2[k] = ws[0] + ws[1] + ws[2] + ws[3];
}

// ---------------- prep_x: x fp16 --------------------------------------------
__global__ void prep_x(const float* __restrict__ x, u16* __restrict__ xh) {
    const int n = blockIdx.x * 4 + (threadIdx.x >> 6);
    const int l = threadIdx.x & 63;
    const float4 v = *(const float4*)&x[(size_t)n * DDIM + l * 4];
    ushort4 h;
    h.x = f2h(v.x); h.y = f2h(v.y); h.z = f2h(v.z); h.w = f2h(v.w);
    *(ushort4*)&xh[(size_t)n * DDIM + l * 4] = h;
}

// ---------------- main: m97-style 128x128 distance GEMM + argmin epilogue ---
// Block (rowblk, cb): rows n0..n0+127 x clusters cb*128..+127. 4 waves (2x2,
// 64x64 each). K=256 in 4 steps of 64, A/B tiles (16KB each) double-buffered
// via global_load_lds with XOR-swizzled layout. 5 barriers per block; next
// tile's loads stay in flight under the current tile's MFMAs (m97 schedule).
__global__ __launch_bounds__(256, 2) void vq_mfma(
        const u16* __restrict__ xh, const u16* __restrict__ eh,
        const float* __restrict__ enorm2,
        float* __restrict__ pm1, int* __restrict__ pi1,
        float* __restrict__ pm2, int N) {
    __shared__ __align__(16) char L[65536];   // [2 bufs][A 16KB | B 16KB]

    const int tid = threadIdx.x;
    const int l   = tid & 63;
    const int w   = tid >> 6;
    const int wr  = w >> 1, wc = w & 1;       // 2x2 wave grid
    const int rowblk = blockIdx.x >> 4;
    const int cb     = blockIdx.x & 15;       // cb inner: 16 blocks share A rows
    const int n0     = rowblk * 128;
    const int c0     = cb * 128;

    // stage one 128x64 fp16 tile pair into buf: LDS[row][c] = global chunk
    // (c ^ (row&7)); dest is linear (gload_lds), source pre-swizzled.
    auto stage = [&](int buf, int kt) {
        const u16* asrc = xh + (size_t)n0 * DDIM + kt * 64;
        const u16* bsrc = eh + (size_t)c0 * DDIM + kt * 64;
        char* Ad = L + buf * 32768;
        char* Bd = Ad + 16384;
        #pragma unroll
        for (int j = 0; j < 4; ++j) {
            const int slot = j * 256 + tid;            // 0..1023
            const int row  = slot >> 3;                // 0..127
            const int gc   = (slot & 7) ^ (row & 7);   // source chunk
            __builtin_amdgcn_global_load_lds(
                (const __attribute__((address_space(1))) void*)(asrc + (size_t)row * DDIM + gc * 8),
                (__attribute__((address_space(3))) void*)(Ad + slot * 16), 16, 0, 0);
        }
        #pragma unroll
        for (int j = 0; j < 4; ++j) {
            const int slot = j * 256 + tid;
            const int row  = slot >> 3;
            const int gc   = (slot & 7) ^ (row & 7);
            __builtin_amdgcn_global_load_lds(
                (const __attribute__((address_space(1))) void*)(bsrc + (size_t)row * DDIM + gc * 8),
                (__attribute__((address_space(3))) void*)(Bd + slot * 16), 16, 0, 0);
        }
    };

    f32x4 acc[4][4];
    #pragma unroll
    for (int a = 0; a < 4; ++a)
        #pragma unroll
        for (int b = 0; b < 4; ++b) acc[a][b] = (f32x4){0.f, 0.f, 0.f, 0.f};

    stage(0, 0);
    __syncthreads();                          // vmcnt(0) drain + barrier

    int cur = 0;
    for (int kt = 0; kt < 4; ++kt) {
        if (kt < 3) stage(cur ^ 1, kt + 1);   // issue next tile (in flight under MFMA)
        const char* Ab = L + cur * 32768;
        const char* Bb = Ab + 16384;
        #pragma unroll
        for (int ks = 0; ks < 2; ++ks) {
            f16x8 af[4], bf[4];
            #pragma unroll
            for (int f = 0; f < 4; ++f) {
                const int arow = wr * 64 + f * 16 + (l & 15);
                const int ac   = (ks * 4 + (l >> 4)) ^ (arow & 7);
                af[f] = *(const f16x8*)(Ab + arow * 128 + ac * 16);
                const int brow = wc * 64 + f * 16 + (l & 15);
                const int bc   = (ks * 4 + (l >> 4)) ^ (brow & 7);
                bf[f] = *(const f16x8*)(Bb + brow * 128 + bc * 16);
            }
            #pragma unroll
            for (int fm = 0; fm < 4; ++fm)
                #pragma unroll
                for (int fn = 0; fn < 4; ++fn)
                    acc[fm][fn] = __builtin_amdgcn_mfma_f32_16x16x32_f16(
                        af[fm], bf[fn], acc[fm][fn], 0, 0, 0);
        }
        __syncthreads();                      // waits next-tile vmcnt + barrier
        cur ^= 1;
    }

    // ---- epilogue: fold 64 distances/lane into (min1, idx, min2), once ----
    float m1[4][4], m2[4][4];
    int   i1[4][4];
    #pragma unroll
    for (int a = 0; a < 4; ++a)
        #pragma unroll
        for (int b = 0; b < 4; ++b) { m1[a][b] = 3.0e38f; m2[a][b] = 3.0e38f; i1[a][b] = 0; }

    #pragma unroll
    for (int fn = 0; fn < 4; ++fn) {
        const int k = c0 + wc * 64 + fn * 16 + (l & 15);
        const float en = enorm2[k];
        #pragma unroll
        for (int fm = 0; fm < 4; ++fm)
            #pragma unroll
            for (int i = 0; i < 4; ++i) {
                const float s = fmaf(-2.0f, acc[fm][fn][i], en);
                const bool lt1 = s < m1[fm][i];
                m2[fm][i] = fminf(m2[fm][i], fmaxf(s, m1[fm][i]));
                i1[fm][i] = lt1 ? k : i1[fm][i];
                m1[fm][i] = fminf(m1[fm][i], s);
            }
    }

    // reduce across the 16 lanes (l&15) sharing each row; ties -> smaller k
    #pragma unroll
    for (int fm = 0; fm < 4; ++fm)
        #pragma unroll
        for (int i = 0; i < 4; ++i) {
            float a1 = m1[fm][i], a2 = m2[fm][i];
            int ai = i1[fm][i];
            #pragma unroll
            for (int mask = 1; mask < 16; mask <<= 1) {
                const float b1 = __shfl_xor(a1, mask, 64);
                const int   bi = __shfl_xor(ai, mask, 64);
                const float b2 = __shfl_xor(a2, mask, 64);
                if (b1 < a1 || (b1 == a1 && bi < ai)) {
                    a2 = fminf(a1, fminf(a2, b2)); a1 = b1; ai = bi;
                } else {
                    a2 = fminf(b1, fminf(a2, b2));
                }
            }
            m1[fm][i] = a1; i1[fm][i] = ai; m2[fm][i] = a2;
        }

    // merge the 2 wave-columns (wc) per row via LDS; write per-cb partials
    float* Sm1 = (float*)L;                    // [128]
    int*   Si1 = (int*)(L + 512);              // [128]
    float* Sm2 = (float*)(L + 1024);           // [128]
    if (wc == 0 && (l & 15) == 0) {
        #pragma unroll
        for (int fm = 0; fm < 4; ++fm)
            #pragma unroll
            for (int i = 0; i < 4; ++i) {
                const int r = wr * 64 + fm * 16 + (l >> 4) * 4 + i;
                Sm1[r] = m1[fm][i]; Si1[r] = i1[fm][i]; Sm2[r] = m2[fm][i];
            }
    }
    __syncthreads();
    if (wc == 1 && (l & 15) == 0) {
        #pragma unroll
        for (int fm = 0; fm < 4; ++fm)
            #pragma unroll
            for (int i = 0; i < 4; ++i) {
                const int r = wr * 64 + fm * 16 + (l >> 4) * 4 + i;
                const float b1 = Sm1[r], b2 = Sm2[r];
                const int   bi = Si1[r];
                float a1 = m1[fm][i], a2 = m2[fm][i];
                int   ai = i1[fm][i];
                float M1, M2; int MI;
                if (b1 < a1 || (b1 == a1 && bi < ai)) {
                    M1 = b1; MI = bi; M2 = fminf(a1, fminf(a2, b2));
                } else {
                    M1 = a1; MI = ai; M2 = fminf(b1, fminf(a2, b2));
                }
                const int n = n0 + r;
                pm1[(size_t)cb * N + n] = M1;
                pi1[(size_t)cb * N + n] = MI;
                pm2[(size_t)cb * N + n] = M2;
            }
    }
}

// ---------------- combine 16 cluster-blocks -> codes + flag list ------------
__global__ void combine(const float* __restrict__ pm1, const int* __restrict__ pi1,
                        const float* __restrict__ pm2,
                        float* __restrict__ codes_f, int* __restrict__ codes_i,
                        int* __restrict__ list, int* __restrict__ counter,
                        u64* __restrict__ packed, int N) {
    const int n = blockIdx.x * 256 + threadIdx.x;
    float M1 = pm1[n], M2 = pm2[n];
    int   MI = pi1[n];
    #pragma unroll
    for (int cb = 1; cb < NCB; ++cb) {
        const float b1 = pm1[(size_t)cb * N + n], b2 = pm2[(size_t)cb * N + n];
        const int   bi = pi1[(size_t)cb * N + n];
        if (b1 < M1 || (b1 == M1 && bi < MI)) {
            M2 = fminf(M1, fminf(M2, b2)); M1 = b1; MI = bi;
        } else {
            M2 = fminf(b1, fminf(M2, b2));
        }
    }
    codes_i[n] = MI;
    codes_f[n] = (float)MI;
    if (M2 - M1 < TAU) {
        packed[n] = 0xFFFFFFFFFFFFFFFFull;
        const int idx = atomicAdd(counter, 1);
        list[idx] = n;
    }
}

// ---------------- rescue_c: exact fp32, 8 rows x 512-cluster work items -----
__global__ __launch_bounds__(256) void rescue_c(
        const float* __restrict__ x, const float* __restrict__ emb_t,
        const float* __restrict__ enorm2,
        const int* __restrict__ list, const int* __restrict__ counter,
        u64* __restrict__ packed, int K) {
    __shared__ float xs[RPB][DDIM];   // 8 KB
    const int t = threadIdx.x;
    const int l = t & 63;
    const int cnt = *counter;
    if (cnt == 0) return;
    const int nblk  = (cnt + RPB - 1) / RPB;
    const int items = nblk * KSPL;
    const int kc    = K / KSPL;       // 512

    for (int wi = blockIdx.x; wi < items; wi += gridDim.x) {
        const int g = wi >> 2;        // KSPL = 4
        const int q = wi & 3;
        const int base = g * RPB;
        int rows[RPB];
        #pragma unroll
        for (int r = 0; r < RPB; ++r) {
            int idx = base + r;
            rows[r] = list[idx < cnt ? idx : cnt - 1];
        }
        __syncthreads();              // previous iteration done reading xs
        #pragma unroll
        for (int r = 0; r < RPB; ++r)
            xs[r][t] = x[(size_t)rows[r] * DDIM + t];
        __syncthreads();

        float acc[RPB][2];
        #pragma unroll
        for (int r = 0; r < RPB; ++r) { acc[r][0] = 0.f; acc[r][1] = 0.f; }

        const float* eb = emb_t + q * kc + 2 * t;
        #pragma unroll 4
        for (int d = 0; d < DDIM; ++d) {
            const float2 e = *(const float2*)&eb[(size_t)d * K];
            #pragma unroll
            for (int r = 0; r < RPB; ++r) {
                const float xv = xs[r][d];
                acc[r][0] = fmaf(xv, e.x, acc[r][0]);
                acc[r][1] = fmaf(xv, e.y, acc[r][1]);
            }
        }

        const int k0 = q * kc + 2 * t;
        const float en0 = enorm2[k0], en1 = enorm2[k0 + 1];
        #pragma unroll
        for (int r = 0; r < RPB; ++r) {
            const float s0 = fmaf(-2.0f, acc[r][0], en0);
            const float s1 = fmaf(-2.0f, acc[r][1], en1);
            float bd = s0; int bk = k0;
            if (s1 < bd) { bd = s1; bk = k0 + 1; }
            #pragma unroll
            for (int m = 1; m < 64; m <<= 1) {
                const float od = __shfl_xor(bd, m, 64);
                const int   ok = __shfl_xor(bk, m, 64);
                if (od < bd || (od == bd && ok < bk)) { bd = od; bk = ok; }
            }
            if (l == 0) atomicMin(&packed[rows[r]], packdk(bd, bk));
        }
    }
}

// ---------------- fixup: unpack rescue winners into codes -------------------
__global__ void fixup(const u64* __restrict__ packed,
                      const int* __restrict__ list, const int* __restrict__ counter,
                      float* __restrict__ codes_f, int* __restrict__ codes_i) {
    const int i = blockIdx.x * 256 + threadIdx.x;
    if (i < *counter) {
        const int n = list[i];
        const int k = (int)(packed[n] & 0xFFFFFFFFull);
        codes_i[n] = k;
        codes_f[n] = (float)k;
    }
}

// ---------------- gather: quantized[n] = emb[code[n]] -----------------------
__global__ void gather_q(const float* __restrict__ emb,
                         const int* __restrict__ codes,
                         float* __restrict__ qout) {
    const int n = blockIdx.x * 4 + (threadIdx.x >> 6);
    const int c = threadIdx.x & 63;
    const int k = codes[n];
    *(float4*)&qout[(size_t)n * DDIM + c * 4] =
        *(const float4*)&emb[(size_t)k * DDIM + c * 4];
}

extern "C" void kernel_launch(void* const* d_in, const int* in_sizes, int n_in,
                              void* d_out, int out_size, void* d_ws, size_t ws_size,
                              hipStream_t stream) {
    const float* x     = (const float*)d_in[0];
    const float* esum  = (const float*)d_in[1];
    const float* usage = (const float*)d_in[2];
    const int K = in_sizes[2];                 // 2048
    const int N = in_sizes[0] / DDIM;          // 32768

    // workspace layout (packed first: 8B alignment)
    char* p = (char*)d_ws;
    u64*   packed  = (u64*)p;                  p += (size_t)N * 8;              // 256 KB
    float* emb     = (float*)p;                p += (size_t)K * DDIM * 4;       // 2 MB
    float* emb_t   = (float*)p;                p += (size_t)K * DDIM * 4;       // 2 MB
    float* enorm2  = (float*)p;                p += (size_t)K * 4;
    float* pm1     = (float*)p;                p += (size_t)NCB * N * 4;        // 2 MB
    float* pm2     = (float*)p;                p += (size_t)NCB * N * 4;        // 2 MB
    int*   pi1     = (int*)p;                  p += (size_t)NCB * N * 4;        // 2 MB
    int*   codes_i = (int*)p;                  p += (size_t)N * 4;
    int*   list    = (int*)p;                  p += (size_t)N * 4;
    int*   counter = (int*)p;                  p += 256;
    u16*   xh      = (u16*)p;                  p += (size_t)N * DDIM * 2;       // 16 MB
    u16*   eh      = (u16*)p;                  p += (size_t)K * DDIM * 2;       // 1 MB

    float* qout    = (float*)d_out;            // N*256
    float* codes_f = qout + (size_t)N * DDIM;  // N

    prep_e<<<K, 256, 0, stream>>>(esum, usage, emb, emb_t, eh, enorm2, counter, K);
    prep_x<<<N / 4, 256, 0, stream>>>(x, xh);
    vq_mfma<<<(N / 128) * NCB, 256, 0, stream>>>(xh, eh, enorm2, pm1, pi1, pm2, N);
    combine<<<N / 256, 256, 0, stream>>>(pm1, pi1, pm2, codes_f, codes_i,
                                         list, counter, packed, N);
    rescue_c<<<1024, 256, 0, stream>>>(x, emb_t, enorm2, list, counter, packed, K);
    fixup<<<N / 256, 256, 0, stream>>>(packed, list, counter, codes_f, codes_i);
    gather_q<<<N / 4, 256, 0, stream>>>(emb, codes_i, qout);
}

// Round 10
// 122.893 us; speedup vs baseline: 1.5087x; 1.5087x over previous
//
#include <hip/hip_runtime.h>

// EuclideanCodebook: fp16 MFMA approx distance (round-4 structure + both-sides
// XOR-swizzled LDS) + top-2 margin flag + split-K exact fp32 rescue.
// x: [N=32768][256] f32, embedding_sum: [K=2048][256] f32, usage: [K] f32
// out: quantized [N*256] f32, codes [N] f32

#define EPSV 1e-5f
#define DDIM 256
#define TAU  0.4f
#define BM   128     // rows per block (vq_mfma)
#define BCL  128     // clusters per tile
#define NCT  8       // cluster tiles per half (1024/128)
#define RPB  8       // rescue rows per group
#define KSPL 4       // rescue K split
#define NROWS 32768

typedef __attribute__((ext_vector_type(8))) _Float16 f16x8;
typedef __attribute__((ext_vector_type(4))) float f32x4;
typedef unsigned short u16;
typedef unsigned long long u64;

__device__ __forceinline__ u16 f2h(float f) {
    f = fminf(fmaxf(f, -60000.f), 60000.f);   // keep fp16 finite
    const _Float16 h = (_Float16)f;
    return __builtin_bit_cast(u16, h);
}
__device__ __forceinline__ u64 packdk(float d, int k) {
    unsigned u = __builtin_bit_cast(unsigned, d);
    u = (u & 0x80000000u) ? ~u : (u | 0x80000000u);   // sortable float
    return ((u64)u << 32) | (unsigned)k;
}

// ---------------- prep_e: emb, emb_t, e fp16, ||e||^2; zero counter ---------
__global__ void prep_e(const float* __restrict__ esum,
                       const float* __restrict__ usage,
                       float* __restrict__ emb,     // [K][256] f32
                       float* __restrict__ emb_t,   // [256][K] f32
                       u16* __restrict__ eh,        // [K][256] f16 bits
                       float* __restrict__ enorm2,  // [K]
                       int* __restrict__ counter,
                       int K) {
    if (blockIdx.x == 0 && threadIdx.x == 0) *counter = 0;
    const int k = blockIdx.x;
    const int d = threadIdx.x;                 // 256 threads
    const float u = fmaxf(usage[k], EPSV);
    const float e = esum[k * DDIM + d] / u;
    emb[k * DDIM + d] = e;
    emb_t[(size_t)d * K + k] = e;
    eh[k * DDIM + d] = f2h(e);

    float s = e * e;
    #pragma unroll
    for (int off = 32; off > 0; off >>= 1) s += __shfl_down(s, off, 64);
    __shared__ float ws[4];
    if ((threadIdx.x & 63) == 0) ws[threadIdx.x >> 6] = s;
    __syncthreads();
    if (threadIdx.x == 0) enorm2[k] = ws[0] + ws[1] + ws[2] + ws[3];
}

// ---------------- prep_x: x fp16 --------------------------------------------
__global__ void prep_x(const float* __restrict__ x, u16* __restrict__ xh) {
    const int n = blockIdx.x * 4 + (threadIdx.x >> 6);
    const int l = threadIdx.x & 63;
    const float4 v = *(const float4*)&x[(size_t)n * DDIM + l * 4];
    ushort4 h;
    h.x = f2h(v.x); h.y = f2h(v.y); h.z = f2h(v.z); h.w = f2h(v.w);
    *(ushort4*)&xh[(size_t)n * DDIM + l * 4] = h;
}

// ---------------- main: fp16 MFMA distance + running (min1, idx, min2) ------
// Round-4 structure: block = 128 rows x 1024 clusters (half), A+B staged per
// (ct,ch) via global_load_lds. NEW: both-sides XOR swizzle — LDS[row][c] holds
// global chunk (c ^ (row&7)); staging pre-swizzles the SOURCE chunk (linear
// dest, gload_lds constraint), frag reads XOR the chunk index. Kills the
// 1.26e7 bank-conflict cycles measured in r4.
__global__ __launch_bounds__(256, 2) void vq_mfma(
        const u16* __restrict__ xh, const u16* __restrict__ eh,
        const float* __restrict__ enorm2,
        float* __restrict__ pm1, int* __restrict__ pi1,
        float* __restrict__ pm2, int N) {
    __shared__ __align__(16) u16 Als[BM * 64];    // 16 KB
    __shared__ __align__(16) u16 Bls[BCL * 64];   // 16 KB

    const int tid = threadIdx.x;
    const int l   = tid & 63;
    const int w   = tid >> 6;            // wave 0..3
    const int wr  = w >> 1, wc = w & 1;  // 2x2 wave grid (64x64 each)
    const int rowblk = blockIdx.x >> 1;
    const int half   = blockIdx.x & 1;
    const int n0     = rowblk * BM;
    const int cbase  = half * 1024;

    float m1[4][4], m2[4][4];
    int   i1[4][4];
    #pragma unroll
    for (int a = 0; a < 4; ++a)
        #pragma unroll
        for (int b = 0; b < 4; ++b) { m1[a][b] = 3.0e38f; m2[a][b] = 3.0e38f; i1[a][b] = 0; }

    // swizzled source chunk for staging: row&7 == (l>>3)&7, chunk == l&7
    const int sgc = (l & 7) ^ ((l >> 3) & 7);

    for (int ct = 0; ct < NCT; ++ct) {
        const int c0 = cbase + ct * BCL;
        f32x4 acc[4][4];
        #pragma unroll
        for (int a = 0; a < 4; ++a)
            #pragma unroll
            for (int b = 0; b < 4; ++b) acc[a][b] = (f32x4){0.f, 0.f, 0.f, 0.f};

        for (int ch = 0; ch < 4; ++ch) {       // 256 = 4 x 64 inner dims
            const int colof = ch * 64;

            __syncthreads();
            #pragma unroll
            for (int j = 0; j < 4; ++j) {
                const int r = (w * 4 + j) * 8 + (l >> 3);
                const u16* ga = xh + (size_t)(n0 + r) * DDIM + colof + sgc * 8;
                __builtin_amdgcn_global_load_lds(
                    (const __attribute__((address_space(1))) void*)ga,
                    (__attribute__((address_space(3))) void*)((char*)Als + (w * 4 + j) * 1024),
                    16, 0, 0);
            }
            #pragma unroll
            for (int j = 0; j < 4; ++j) {
                const int r = (w * 4 + j) * 8 + (l >> 3);
                const u16* gb = eh + (size_t)(c0 + r) * DDIM + colof + sgc * 8;
                __builtin_amdgcn_global_load_lds(
                    (const __attribute__((address_space(1))) void*)gb,
                    (__attribute__((address_space(3))) void*)((char*)Bls + (w * 4 + j) * 1024),
                    16, 0, 0);
            }
            __syncthreads();

            #pragma unroll
            for (int ks = 0; ks < 2; ++ks) {
                f16x8 af[4], bfr[4];
                #pragma unroll
                for (int f = 0; f < 4; ++f) {
                    const int arow = wr * 64 + f * 16 + (l & 15);
                    const int ac   = (ks * 4 + (l >> 4)) ^ (l & 7);   // arow&7 == l&7
                    af[f] = *(const f16x8*)((const char*)Als + arow * 128 + ac * 16);
                    const int brow = wc * 64 + f * 16 + (l & 15);
                    const int bc   = (ks * 4 + (l >> 4)) ^ (l & 7);
                    bfr[f] = *(const f16x8*)((const char*)Bls + brow * 128 + bc * 16);
                }
                #pragma unroll
                for (int fm = 0; fm < 4; ++fm)
                    #pragma unroll
                    for (int fn = 0; fn < 4; ++fn)
                        acc[fm][fn] = __builtin_amdgcn_mfma_f32_16x16x32_f16(
                            af[fm], bfr[fn], acc[fm][fn], 0, 0, 0);
            }
        }

        // fold into running (min1, idx, min2); k ascending
        #pragma unroll
        for (int fn = 0; fn < 4; ++fn) {
            const int k = c0 + wc * 64 + fn * 16 + (l & 15);
            const float en = enorm2[k];
            #pragma unroll
            for (int fm = 0; fm < 4; ++fm)
                #pragma unroll
                for (int i = 0; i < 4; ++i) {
                    const float s = fmaf(-2.0f, acc[fm][fn][i], en);
                    const bool lt1 = s < m1[fm][i];
                    m2[fm][i] = fminf(m2[fm][i], fmaxf(s, m1[fm][i]));
                    i1[fm][i] = lt1 ? k : i1[fm][i];
                    m1[fm][i] = fminf(m1[fm][i], s);
                }
        }
    }

    // reduce across the 16 lanes (l&15) sharing each row; ties -> smaller k
    #pragma unroll
    for (int fm = 0; fm < 4; ++fm)
        #pragma unroll
        for (int i = 0; i < 4; ++i) {
            float a1 = m1[fm][i], a2 = m2[fm][i];
            int ai = i1[fm][i];
            #pragma unroll
            for (int mask = 1; mask < 16; mask <<= 1) {
                const float b1 = __shfl_xor(a1, mask, 64);
                const int   bi = __shfl_xor(ai, mask, 64);
                const float b2 = __shfl_xor(a2, mask, 64);
                if (b1 < a1 || (b1 == a1 && bi < ai)) {
                    a2 = fminf(a1, fminf(a2, b2)); a1 = b1; ai = bi;
                } else {
                    a2 = fminf(b1, fminf(a2, b2));
                }
            }
            m1[fm][i] = a1; i1[fm][i] = ai; m2[fm][i] = a2;
        }

    // merge the two wave-columns via LDS, write per-(half,row) partials
    __syncthreads();
    float* Sm1 = (float*)Als;
    int*   Si1 = (int*)((char*)Als + 512);
    float* Sm2 = (float*)((char*)Als + 1024);
    if (wc == 0 && (l & 15) == 0) {
        #pragma unroll
        for (int fm = 0; fm < 4; ++fm)
            #pragma unroll
            for (int i = 0; i < 4; ++i) {
                const int r = wr * 64 + fm * 16 + (l >> 4) * 4 + i;
                Sm1[r] = m1[fm][i]; Si1[r] = i1[fm][i]; Sm2[r] = m2[fm][i];
            }
    }
    __syncthreads();
    if (wc == 1 && (l & 15) == 0) {
        #pragma unroll
        for (int fm = 0; fm < 4; ++fm)
            #pragma unroll
            for (int i = 0; i < 4; ++i) {
                const int r = wr * 64 + fm * 16 + (l >> 4) * 4 + i;
                const float b1 = Sm1[r], b2 = Sm2[r];
                const int   bi = Si1[r];
                float a1 = m1[fm][i], a2 = m2[fm][i];
                int   ai = i1[fm][i];
                float M1, M2; int MI;
                if (b1 < a1 || (b1 == a1 && bi < ai)) {
                    M1 = b1; MI = bi; M2 = fminf(a1, fminf(a2, b2));
                } else {
                    M1 = a1; MI = ai; M2 = fminf(b1, fminf(a2, b2));
                }
                const int n = n0 + r;
                pm1[(size_t)half * N + n] = M1;
                pi1[(size_t)half * N + n] = MI;
                pm2[(size_t)half * N + n] = M2;
            }
    }
}

// ---------------- combine halves -> codes + flag list + packed init ---------
__global__ void combine(const float* __restrict__ pm1, const int* __restrict__ pi1,
                        const float* __restrict__ pm2,
                        float* __restrict__ codes_f, int* __restrict__ codes_i,
                        int* __restrict__ list, int* __restrict__ counter,
                        u64* __restrict__ packed, int N) {
    const int n = blockIdx.x * 256 + threadIdx.x;
    const float a1 = pm1[n], a2 = pm2[n];
    const int   ai = pi1[n];
    const float b1 = pm1[(size_t)N + n], b2 = pm2[(size_t)N + n];
    const int   bi = pi1[(size_t)N + n];
    float M1, M2; int MI;
    if (b1 < a1 || (b1 == a1 && bi < ai)) {
        M1 = b1; MI = bi; M2 = fminf(a1, fminf(a2, b2));
    } else {
        M1 = a1; MI = ai; M2 = fminf(b1, fminf(a2, b2));
    }
    codes_i[n] = MI;
    codes_f[n] = (float)MI;
    if (M2 - M1 < TAU) {
        packed[n] = 0xFFFFFFFFFFFFFFFFull;
        const int idx = atomicAdd(counter, 1);
        list[idx] = n;
    }
}

// ---------------- rescue_c: exact fp32, 8 rows x 512-cluster work items -----
__global__ __launch_bounds__(256) void rescue_c(
        const float* __restrict__ x, const float* __restrict__ emb_t,
        const float* __restrict__ enorm2,
        const int* __restrict__ list, const int* __restrict__ counter,
        u64* __restrict__ packed, int K) {
    __shared__ float xs[RPB][DDIM];   // 8 KB
    const int t = threadIdx.x;
    const int l = t & 63;
    int cnt = *counter;
    cnt = cnt < 0 ? 0 : (cnt > NROWS ? NROWS : cnt);   // defensive clamp
    if (cnt == 0) return;
    const int nblk  = (cnt + RPB - 1) / RPB;
    const int items = nblk * KSPL;
    const int kc    = K / KSPL;       // 512

    for (int wi = blockIdx.x; wi < items; wi += gridDim.x) {
        const int g = wi >> 2;        // KSPL = 4
        const int q = wi & 3;
        const int base = g * RPB;
        int rows[RPB];
        #pragma unroll
        for (int r = 0; r < RPB; ++r) {
            int idx = base + r;
            rows[r] = list[idx < cnt ? idx : cnt - 1];
        }
        __syncthreads();              // previous iteration done reading xs
        #pragma unroll
        for (int r = 0; r < RPB; ++r)
            xs[r][t] = x[(size_t)rows[r] * DDIM + t];
        __syncthreads();

        float acc[RPB][2];
        #pragma unroll
        for (int r = 0; r < RPB; ++r) { acc[r][0] = 0.f; acc[r][1] = 0.f; }

        const float* eb = emb_t + q * kc + 2 * t;
        #pragma unroll 4
        for (int d = 0; d < DDIM; ++d) {
            const float2 e = *(const float2*)&eb[(size_t)d * K];
            #pragma unroll
            for (int r = 0; r < RPB; ++r) {
                const float xv = xs[r][d];
                acc[r][0] = fmaf(xv, e.x, acc[r][0]);
                acc[r][1] = fmaf(xv, e.y, acc[r][1]);
            }
        }

        const int k0 = q * kc + 2 * t;
        const float en0 = enorm2[k0], en1 = enorm2[k0 + 1];
        #pragma unroll
        for (int r = 0; r < RPB; ++r) {
            const float s0 = fmaf(-2.0f, acc[r][0], en0);
            const float s1 = fmaf(-2.0f, acc[r][1], en1);
            float bd = s0; int bk = k0;
            if (s1 < bd) { bd = s1; bk = k0 + 1; }
            #pragma unroll
            for (int m = 1; m < 64; m <<= 1) {
                const float od = __shfl_xor(bd, m, 64);
                const int   ok = __shfl_xor(bk, m, 64);
                if (od < bd || (od == bd && ok < bk)) { bd = od; bk = ok; }
            }
            if (l == 0) atomicMin(&packed[rows[r]], packdk(bd, bk));
        }
    }
}

// ---------------- fixup: unpack rescue winners into codes -------------------
__global__ void fixup(const u64* __restrict__ packed,
                      const int* __restrict__ list, const int* __restrict__ counter,
                      float* __restrict__ codes_f, int* __restrict__ codes_i) {
    int cnt = *counter;
    cnt = cnt < 0 ? 0 : (cnt > NROWS ? NROWS : cnt);   // defensive clamp
    const int i = blockIdx.x * 256 + threadIdx.x;
    if (i < cnt) {
        const int n = list[i];
        const int k = (int)(packed[n] & 0xFFFFFFFFull);
        codes_i[n] = k;
        codes_f[n] = (float)k;
    }
}

// ---------------- gather: quantized[n] = emb[code[n]] -----------------------
__global__ void gather_q(const float* __restrict__ emb,
                         const int* __restrict__ codes,
                         float* __restrict__ qout) {
    const int n = blockIdx.x * 4 + (threadIdx.x >> 6);
    const int c = threadIdx.x & 63;
    const int k = codes[n];
    *(float4*)&qout[(size_t)n * DDIM + c * 4] =
        *(const float4*)&emb[(size_t)k * DDIM + c * 4];
}

extern "C" void kernel_launch(void* const* d_in, const int* in_sizes, int n_in,
                              void* d_out, int out_size, void* d_ws, size_t ws_size,
                              hipStream_t stream) {
    const float* x     = (const float*)d_in[0];
    const float* esum  = (const float*)d_in[1];
    const float* usage = (const float*)d_in[2];
    const int K = in_sizes[2];                 // 2048
    const int N = in_sizes[0] / DDIM;          // 32768

    // workspace layout (packed first: 8B alignment)
    char* p = (char*)d_ws;
    u64*   packed  = (u64*)p;                  p += (size_t)N * 8;          // 256 KB
    float* emb     = (float*)p;                p += (size_t)K * DDIM * 4;   // 2 MB
    float* emb_t   = (float*)p;                p += (size_t)K * DDIM * 4;   // 2 MB
    float* enorm2  = (float*)p;                p += (size_t)K * 4;
    float* pm1     = (float*)p;                p += (size_t)2 * N * 4;
    float* pm2     = (float*)p;                p += (size_t)2 * N * 4;
    int*   pi1     = (int*)p;                  p += (size_t)2 * N * 4;
    int*   codes_i = (int*)p;                  p += (size_t)N * 4;
    int*   list    = (int*)p;                  p += (size_t)N * 4;
    int*   counter = (int*)p;                  p += 256;
    u16*   xh      = (u16*)p;                  p += (size_t)N * DDIM * 2;   // 16 MB
    u16*   eh      = (u16*)p;                  p += (size_t)K * DDIM * 2;   // 1 MB

    float* qout    = (float*)d_out;            // N*256
    float* codes_f = qout + (size_t)N * DDIM;  // N

    prep_e<<<K, 256, 0, stream>>>(esum, usage, emb, emb_t, eh, enorm2, counter, K);
    prep_x<<<N / 4, 256, 0, stream>>>(x, xh);
    vq_mfma<<<(N / BM) * 2, 256, 0, stream>>>(xh, eh, enorm2, pm1, pi1, pm2, N);
    combine<<<N / 256, 256, 0, stream>>>(pm1, pi1, pm2, codes_f, codes_i,
                                         list, counter, packed, N);
    rescue_c<<<1024, 256, 0, stream>>>(x, emb_t, enorm2, list, counter, packed, K);
    fixup<<<N / 256, 256, 0, stream>>>(packed, list, counter, codes_f, codes_i);
    gather_q<<<N / 4, 256, 0, stream>>>(emb, codes_i, qout);
}